// Round 4
// baseline (165.898 us; speedup 1.0000x reference)
//
#include <hip/hip_runtime.h>

#define BINS 4096            // 64 * 64
#define HIST_BLOCKS 1024
#define HIST_THREADS 512     // 8 waves/block, 4 blocks/CU -> 32 waves/CU
#define U 4                  // unpredicated int4-pairs batched per iteration

// out[i] = transitions_in[i] for i < bins; out[bins] = total_in + n_events
__global__ void topo_init_kernel(const float* __restrict__ transitions,
                                 const float* __restrict__ total,
                                 float* __restrict__ out,
                                 float n_events_f, int bins) {
    int i = blockIdx.x * blockDim.x + threadIdx.x;
    if (i < bins) out[i] = transitions[i];
    if (i == 0) out[bins] = total[0] + n_events_f;
}

// Exact-partition kernel: requires n4 % (gridDim.x * HIST_THREADS * U) == 0.
// No bounds checks -> compiler batches all 2*U dwordx4 loads before waiting.
__global__ void __launch_bounds__(HIST_THREADS, 8)
topo_hist_exact(const int* __restrict__ prev,
                const int* __restrict__ curr,
                float* __restrict__ out, int n4) {
    __shared__ unsigned h[BINS];
    for (int i = threadIdx.x; i < BINS; i += HIST_THREADS) h[i] = 0u;
    __syncthreads();

    const int4* __restrict__ p4 = (const int4*)prev;
    const int4* __restrict__ c4 = (const int4*)curr;

    const int chunk = HIST_THREADS * U;
    const int step  = gridDim.x * chunk;

    for (int s = blockIdx.x * chunk + threadIdx.x; s < n4; s += step) {
        int4 p[U], c[U];
#pragma unroll
        for (int j = 0; j < U; j++) {
            p[j] = p4[s + j * HIST_THREADS];
            c[j] = c4[s + j * HIST_THREADS];
        }
#pragma unroll
        for (int j = 0; j < U; j++) {
            atomicAdd(&h[(p[j].x << 6) | c[j].x], 1u);
            atomicAdd(&h[(p[j].y << 6) | c[j].y], 1u);
            atomicAdd(&h[(p[j].z << 6) | c[j].z], 1u);
            atomicAdd(&h[(p[j].w << 6) | c[j].w], 1u);
        }
    }

    __syncthreads();
    for (int i = threadIdx.x; i < BINS; i += HIST_THREADS) {
        unsigned cnt = h[i];
        if (cnt) atomicAdd(&out[i], (float)cnt);
    }
}

// Fallback for arbitrary n (predicated, grid-stride).
__global__ void __launch_bounds__(HIST_THREADS)
topo_hist_generic(const int* __restrict__ prev,
                  const int* __restrict__ curr,
                  float* __restrict__ out, int n) {
    __shared__ unsigned h[BINS];
    for (int i = threadIdx.x; i < BINS; i += HIST_THREADS) h[i] = 0u;
    __syncthreads();

    const int tid = blockIdx.x * HIST_THREADS + threadIdx.x;
    const int stride = gridDim.x * HIST_THREADS;
    for (int i = tid; i < n; i += stride)
        atomicAdd(&h[(prev[i] << 6) | curr[i]], 1u);

    __syncthreads();
    for (int i = threadIdx.x; i < BINS; i += HIST_THREADS) {
        unsigned cnt = h[i];
        if (cnt) atomicAdd(&out[i], (float)cnt);
    }
}

extern "C" void kernel_launch(void* const* d_in, const int* in_sizes, int n_in,
                              void* d_out, int out_size, void* d_ws, size_t ws_size,
                              hipStream_t stream) {
    const int*   prev        = (const int*)d_in[0];
    const int*   curr        = (const int*)d_in[1];
    const float* transitions = (const float*)d_in[2];
    const float* total       = (const float*)d_in[3];
    float* out = (float*)d_out;

    const int n    = in_sizes[0];
    const int bins = in_sizes[2];   // 4096

    // 1) initialize output: copy transitions input, set total = total_in + n
    int init_blocks = (bins + 1 + 255) / 256;
    topo_init_kernel<<<init_blocks, 256, 0, stream>>>(transitions, total, out,
                                                      (float)n, bins);

    const int n4 = n >> 2;
    const long long per_pass = (long long)HIST_BLOCKS * HIST_THREADS * U;
    if (bins == BINS && (n & 3) == 0 && (n4 % per_pass) == 0) {
        topo_hist_exact<<<HIST_BLOCKS, HIST_THREADS, 0, stream>>>(prev, curr,
                                                                  out, n4);
    } else {
        topo_hist_generic<<<HIST_BLOCKS, HIST_THREADS, 0, stream>>>(prev, curr,
                                                                    out, n);
    }
}

// Round 5
// 157.351 us; speedup vs baseline: 1.0543x; 1.0543x over previous
//
#include <hip/hip_runtime.h>

#define BINS 4096            // 64 * 64
#define HIST_BLOCKS 1024
#define HIST_THREADS 512     // 8 waves/block, 4 blocks/CU -> 32 waves/CU
#define PT 8                 // int4-pairs per thread (exact: 1024*512*8*4 = 16.7M)

// out[i] = transitions_in[i] for i < bins; out[bins] = total_in + n_events
__global__ void topo_init_kernel(const float* __restrict__ transitions,
                                 const float* __restrict__ total,
                                 float* __restrict__ out,
                                 float n_events_f, int bins) {
    int i = blockIdx.x * blockDim.x + threadIdx.x;
    if (i < bins) out[i] = transitions[i];
    if (i == 0) out[bins] = total[0] + n_events_f;
}

// Exact-partition, software-pipelined: loads for pair j+1 are issued BEFORE
// the LDS atomics of pair j, so the compiler can wait with partial vmcnt and
// keep the DS pipe busy during global-load latency. Requires
// n == HIST_BLOCKS*HIST_THREADS*PT*4.
__global__ void __launch_bounds__(HIST_THREADS, 8)
topo_hist_exact(const int* __restrict__ prev,
                const int* __restrict__ curr,
                float* __restrict__ out) {
    __shared__ unsigned h[BINS];

    const int4* __restrict__ p4 = (const int4*)prev;
    const int4* __restrict__ c4 = (const int4*)curr;
    const int base = blockIdx.x * (HIST_THREADS * PT) + threadIdx.x;

    // Prefetch first pair before LDS init so its latency overlaps the init.
    int4 pc = p4[base];
    int4 cc = c4[base];

    for (int i = threadIdx.x; i < BINS; i += HIST_THREADS) h[i] = 0u;
    __syncthreads();

#pragma unroll
    for (int j = 1; j < PT; ++j) {
        int4 pn = p4[base + j * HIST_THREADS];   // prefetch next pair
        int4 cn = c4[base + j * HIST_THREADS];
        atomicAdd(&h[(pc.x << 6) | cc.x], 1u);   // consume current pair
        atomicAdd(&h[(pc.y << 6) | cc.y], 1u);
        atomicAdd(&h[(pc.z << 6) | cc.z], 1u);
        atomicAdd(&h[(pc.w << 6) | cc.w], 1u);
        pc = pn; cc = cn;                        // rotate
    }
    atomicAdd(&h[(pc.x << 6) | cc.x], 1u);
    atomicAdd(&h[(pc.y << 6) | cc.y], 1u);
    atomicAdd(&h[(pc.z << 6) | cc.z], 1u);
    atomicAdd(&h[(pc.w << 6) | cc.w], 1u);

    __syncthreads();
    for (int i = threadIdx.x; i < BINS; i += HIST_THREADS) {
        unsigned cnt = h[i];
        if (cnt) atomicAdd(&out[i], (float)cnt);
    }
}

// Fallback for arbitrary n (predicated, grid-stride).
__global__ void __launch_bounds__(HIST_THREADS)
topo_hist_generic(const int* __restrict__ prev,
                  const int* __restrict__ curr,
                  float* __restrict__ out, int n) {
    __shared__ unsigned h[BINS];
    for (int i = threadIdx.x; i < BINS; i += HIST_THREADS) h[i] = 0u;
    __syncthreads();

    const int tid = blockIdx.x * HIST_THREADS + threadIdx.x;
    const int stride = gridDim.x * HIST_THREADS;
    for (int i = tid; i < n; i += stride)
        atomicAdd(&h[(prev[i] << 6) | curr[i]], 1u);

    __syncthreads();
    for (int i = threadIdx.x; i < BINS; i += HIST_THREADS) {
        unsigned cnt = h[i];
        if (cnt) atomicAdd(&out[i], (float)cnt);
    }
}

extern "C" void kernel_launch(void* const* d_in, const int* in_sizes, int n_in,
                              void* d_out, int out_size, void* d_ws, size_t ws_size,
                              hipStream_t stream) {
    const int*   prev        = (const int*)d_in[0];
    const int*   curr        = (const int*)d_in[1];
    const float* transitions = (const float*)d_in[2];
    const float* total       = (const float*)d_in[3];
    float* out = (float*)d_out;

    const int n    = in_sizes[0];
    const int bins = in_sizes[2];   // 4096

    // 1) initialize output: copy transitions input, set total = total_in + n
    int init_blocks = (bins + 1 + 255) / 256;
    topo_init_kernel<<<init_blocks, 256, 0, stream>>>(transitions, total, out,
                                                      (float)n, bins);

    const long long exact_n = (long long)HIST_BLOCKS * HIST_THREADS * PT * 4;
    if (bins == BINS && (long long)n == exact_n) {
        topo_hist_exact<<<HIST_BLOCKS, HIST_THREADS, 0, stream>>>(prev, curr,
                                                                  out);
    } else {
        topo_hist_generic<<<HIST_BLOCKS, HIST_THREADS, 0, stream>>>(prev, curr,
                                                                    out, n);
    }
}